// Round 10
// baseline (95.654 us; speedup 1.0000x reference)
//
#include <hip/hip_runtime.h>

// ConvSBS fused, R8: R7b's verified all-MFMA pipeline, re-packed into
// 64-thread (1-wave) blocks. Wave is fully self-contained (wave-private
// LDS, PIN-ordered in-order DS pipe), so smaller blocks cost nothing and
// LDS/block drops 61->14.7 KB => 10 blocks/CU (2.5 waves/SIMD) vs 2x256.
// Also: E-stage 4-deep MFMA chain split into two independent 2-chains.
//  stage A: t[qlr, px] = W(512x16).P(16x8) -> LDS px slots      [R6-verified]
//  stage B: Ct = M1T.M0T, D = M2.M3T per px (16x16x16, K=8 pad) [R7b-verified]
//  stage E: 4 px per MFMA chain, block-diagonal batching        [R7b-verified]

typedef __fp16 h2 __attribute__((ext_vector_type(2)));
typedef __fp16 h4 __attribute__((ext_vector_type(4)));
typedef float  f4 __attribute__((ext_vector_type(4)));

#define NB 8
#define NH 128
#define NW 128
#define HO 127
#define WO 127
#define CH1_OFF (NB*NH*NW*4)   // 524288 floats
#define PXSTR 648              // halfs per px slot: 640 data + 8 pad
#define ZOFF  640              // zeroed 4-half pad inside each slot
#define CDROW 68               // C'/D' row stride (halfs)
#define CDSTR 544              // per-px C'/D' stride = 8*68
#define SS    20               // sbuf row stride (floats)

#define PIN() asm volatile("" ::: "memory")
#define PKRTZ(a, b) __builtin_amdgcn_cvt_pkrtz((a), (b))

__device__ __forceinline__ f4 mfma16(h4 a, h4 b, f4 c) {
  return __builtin_amdgcn_mfma_f32_16x16x16f16(a, b, c, 0, 0, 0);
}

__global__ __launch_bounds__(64, 3)
void convsbs_fused(const float* __restrict__ ch,
                   const float* __restrict__ cores,
                   float* __restrict__ out) {
  const int lane = threadIdx.x & 63;
  const int quad = lane >> 4;   // MFMA k-group / C-row group
  const int nn   = lane & 15;   // MFMA m/n index
  const int x8   = lane & 7;
  const f4 F4Z = {0.f, 0.f, 0.f, 0.f};

  __shared__ __align__(16) __fp16 tbuf[8 * PXSTR];   // 10368 B
  __shared__ __align__(16) __fp16 cdb[4 * CDSTR];    //  4352 B
  __shared__ __align__(16) float  sbuf[4 * SS];      //   320 B

  // zero the K=8 pad target in each px slot (read by quads 2,3 in stage B)
  if (lane < 8) *(h4*)(tbuf + lane * PXSTR + ZOFF) = (h4){0, 0, 0, 0};
  PIN();

  // stage-A write base (nn<8; cols 8-15 duplicate)  [R6-verified]
  __fp16* wrbase = tbuf + nn * PXSTR + quad * 4;
  const bool wr = (nn < 8);

  // ---- W as 32 A-fragments (R5b/R6-verified)
  h4 wf[4][8];
#pragma unroll
  for (int c = 0; c < 4; ++c)
#pragma unroll
    for (int bi = 0; bi < 8; ++bi) {
      const int rowIdx = bi * 16 + nn;
      const int q  = rowIdx >> 6;
      const int ua = (rowIdx >> 3) & 7;
      const int ub = rowIdx & 7;
      const int l = (c & 1) ? ub : ua;
      const int r = (c & 1) ? ua : ub;
      const float4 wv = *(const float4*)(
          cores + ((((c * 2 + q) * 8 + l) * 8 + r) << 4) + quad * 4);
      h2 p0 = PKRTZ(wv.x, wv.y), p1 = PKRTZ(wv.z, wv.w);
      wf[c][bi] = (h4){p0[0], p0[1], p1[0], p1[1]};
    }

  // ---- hoisted, lane-constant stage-B/E LDS offsets (halfs) [R7b-verified]
  const int hq = nn >> 3, hb = nn & 7;
  const int ctA = (quad < 2) ? ((2 + hq) * 80 + hb * 8 + quad * 4) : ZOFF;
  const int ctB = (quad < 2) ? ( hq      * 80 + hb * 8 + quad * 4) : ZOFF;
  const int dA  = (quad < 2) ? ((4 + hq) * 80 + hb * 8 + quad * 4) : ZOFF;
  const int dB  = (quad < 2) ? ((6 + hq) * 80 + hb * 8 + quad * 4) : ZOFF;
  const int ctW = (hq * 2 + (quad >> 1)) * CDROW + hb * 8 + (quad & 1) * 4;
  const int dW  = (4 + (quad >> 1) * 2 + hq) * CDROW + hb * 8 + (quad & 1) * 4;
  const int eA  = (nn >> 2) * CDSTR + (nn & 3) * CDROW + quad * 4;
  const int eB  = (nn >> 2) * CDSTR + (4 + (nn & 3)) * CDROW + quad * 4;
  const bool sW = ((nn >> 2) == quad);
  const int sWo = quad * SS + (nn & 3) * 4;
  const int sRo = quad * SS + (nn & 3) * 4 + (nn >> 2);

  // block = (b, y, x-quarter)
  const int blk = blockIdx.x;
  const int by  = blk >> 2;
  const int b   = by / 127;
  const int y   = by - b * 127;
  const int xq  = (blk & 3) * 32;
  const float* rowbase = ch + (size_t)((b * NH + y) * NW) * 4;
  float* obase = out + (size_t)((b * HO + y) * WO) * 16;

  float  a0[2][4];
  float4 a1[2][4];
  auto loadch = [&](int xtile, int bufi) {
#pragma unroll
    for (int c = 0; c < 4; ++c) {
      int col = xtile + x8 + (c & 1);
      col = col > 127 ? 127 : col;
      const float* cp = rowbase + (((c >> 1) * NW) + col) * 4;
      a0[bufi][c] = cp[quad];
      a1[bufi][c] = *(const float4*)(cp + CH1_OFF);
    }
  };

  loadch(xq, 0);

#pragma unroll
  for (int t = 0; t < 4; ++t) {
    const int cb = t & 1;

    // ---- stage A: B-frags + 32 MFMA + masked b64 writes [R6-verified]
    h4 bf[4];
#pragma unroll
    for (int c = 0; c < 4; ++c) {
      const float s = a0[cb][c];
      const float4 v = a1[cb][c];
      h2 p0 = PKRTZ(s * v.x, s * v.y), p1 = PKRTZ(s * v.z, s * v.w);
      bf[c] = (h4){p0[0], p0[1], p1[0], p1[1]};
    }
    if (t < 3) loadch(xq + (t + 1) * 8, cb ^ 1);

#pragma unroll
    for (int c = 0; c < 4; ++c)
#pragma unroll
      for (int bi = 0; bi < 8; ++bi) {
        f4 acc = mfma16(wf[c][bi], bf[c], F4Z);
        h2 p0 = PKRTZ(acc[0], acc[1]), p1 = PKRTZ(acc[2], acc[3]);
        if (wr)
          *(h4*)(wrbase + c * 160 + bi * 16 + (bi >= 4 ? 16 : 0)) =
              (h4){p0[0], p0[1], p1[0], p1[1]};
      }
    PIN();

    // ---- stage B + E, two 4-px groups [R7b-verified]
#pragma unroll
    for (int g = 0; g < 2; ++g) {
#pragma unroll
      for (int p4 = 0; p4 < 4; ++p4) {
        const __fp16* slot = tbuf + (g * 4 + p4) * PXSTR;
        __fp16* cd = cdb + p4 * CDSTR;
        h4 a1f = *(const h4*)(slot + ctA);
        h4 b1f = *(const h4*)(slot + ctB);
        f4 c0 = mfma16(a1f, b1f, F4Z);
        h2 u0 = PKRTZ(c0[0], c0[1]), u1 = PKRTZ(c0[2], c0[3]);
        *(h4*)(cd + ctW) = (h4){u0[0], u0[1], u1[0], u1[1]};
        h4 a2f = *(const h4*)(slot + dA);
        h4 b2f = *(const h4*)(slot + dB);
        f4 d0 = mfma16(a2f, b2f, F4Z);
        h2 v0 = PKRTZ(d0[0], d0[1]), v1 = PKRTZ(d0[2], d0[3]);
        *(h4*)(cd + dW) = (h4){v0[0], v0[1], v1[0], v1[1]};
      }
      PIN();

      // ---- E: 4 px per chain (K=64, diagonal px blocks), 2 parallel chains
      f4 e0 = F4Z, e1 = F4Z;
      {
        h4 ea0 = *(const h4*)(cdb + eA);
        h4 eb0 = *(const h4*)(cdb + eB);
        h4 ea1 = *(const h4*)(cdb + eA + 16);
        h4 eb1 = *(const h4*)(cdb + eB + 16);
        h4 ea2 = *(const h4*)(cdb + eA + 32);
        h4 eb2 = *(const h4*)(cdb + eB + 32);
        h4 ea3 = *(const h4*)(cdb + eA + 48);
        h4 eb3 = *(const h4*)(cdb + eB + 48);
        e0 = mfma16(ea0, eb0, e0); e0 = mfma16(ea2, eb2, e0);
        e1 = mfma16(ea1, eb1, e1); e1 = mfma16(ea3, eb3, e1);
      }
      const f4 e = e0 + e1;
      if (sW) *(float4*)(sbuf + sWo) = make_float4(e[0], e[1], e[2], e[3]);
      PIN();

      // coalesced 256B store: lane (quad=px, nn=o16)
      const float v = sbuf[sRo];
      const int x4 = xq + t * 8 + g * 4 + quad;
      if (x4 < WO) obase[x4 * 16 + nn] = v;
      PIN();
    }
  }
}

extern "C" void kernel_launch(void* const* d_in, const int* in_sizes, int n_in,
                              void* d_out, int out_size, void* d_ws, size_t ws_size,
                              hipStream_t stream) {
  (void)in_sizes; (void)n_in; (void)d_ws; (void)ws_size; (void)out_size;
  const float* ch    = (const float*)d_in[0];  // [2,8,128,128,4] f32
  const float* cores = (const float*)d_in[1];  // [4,2,8,8,4,4]   f32
  float* out = (float*)d_out;                  // [8,127,127,16]  f32
  convsbs_fused<<<8 * 127 * 4, 64, 0, stream>>>(ch, cores, out);
}

// Round 11
// 86.518 us; speedup vs baseline: 1.1056x; 1.1056x over previous
//
#include <hip/hip_runtime.h>

// ConvSBS fused, R9: same verified all-MFMA layouts as R7b/R8, restructured
// t-loop for ILP: B(all 8 px) | PIN | E-reads + stageA(t+1) + E-MFMAs+stores.
// Widens the independent-DS window per waitcnt ~3x; stage A(t+1) (32 MFMAs +
// global prefetch, cdb-independent) fills E's ds_read latency shadow.
//  stage A: t[qlr, px] = W(512x16).P(16x8) -> LDS px slots      [R6-verified]
//  stage B: Ct = M1T.M0T, D = M2.M3T per px (16x16x16, K=8 pad) [R7b-verified]
//  stage E: 4 px per MFMA chain, block-diagonal batching        [R7b-verified]

typedef __fp16 h2 __attribute__((ext_vector_type(2)));
typedef __fp16 h4 __attribute__((ext_vector_type(4)));
typedef float  f4 __attribute__((ext_vector_type(4)));

#define NB 8
#define NH 128
#define NW 128
#define HO 127
#define WO 127
#define CH1_OFF (NB*NH*NW*4)   // 524288 floats
#define PXSTR 648              // halfs per px slot: 640 data + 8 pad
#define ZOFF  640              // zeroed 4-half pad inside each slot
#define CDROW 68               // C'/D' row stride (halfs)
#define CDSTR 544              // per-px C'/D' stride = 8*68
#define SS    20               // sbuf row stride (floats)

#define PIN() asm volatile("" ::: "memory")
#define PKRTZ(a, b) __builtin_amdgcn_cvt_pkrtz((a), (b))

__device__ __forceinline__ f4 mfma16(h4 a, h4 b, f4 c) {
  return __builtin_amdgcn_mfma_f32_16x16x16f16(a, b, c, 0, 0, 0);
}

__global__ __launch_bounds__(64, 2)
void convsbs_fused(const float* __restrict__ ch,
                   const float* __restrict__ cores,
                   float* __restrict__ out) {
  const int lane = threadIdx.x & 63;
  const int quad = lane >> 4;   // MFMA k-group / C-row group
  const int nn   = lane & 15;   // MFMA m/n index
  const int x8   = lane & 7;
  const f4 F4Z = {0.f, 0.f, 0.f, 0.f};

  __shared__ __align__(16) __fp16 tbuf[8 * PXSTR];   // 10368 B
  __shared__ __align__(16) __fp16 cdb[8 * CDSTR];    //  8704 B (8 px now)
  __shared__ __align__(16) float  sbuf[2][4 * SS];   //   640 B

  // zero the K=8 pad target in each px slot (read by quads 2,3 in stage B)
  if (lane < 8) *(h4*)(tbuf + lane * PXSTR + ZOFF) = (h4){0, 0, 0, 0};
  PIN();

  // stage-A write base (nn<8; cols 8-15 duplicate)  [R6-verified]
  __fp16* wrbase = tbuf + nn * PXSTR + quad * 4;
  const bool wr = (nn < 8);

  // ---- W as 32 A-fragments (R5b/R6-verified)
  h4 wf[4][8];
#pragma unroll
  for (int c = 0; c < 4; ++c)
#pragma unroll
    for (int bi = 0; bi < 8; ++bi) {
      const int rowIdx = bi * 16 + nn;
      const int q  = rowIdx >> 6;
      const int ua = (rowIdx >> 3) & 7;
      const int ub = rowIdx & 7;
      const int l = (c & 1) ? ub : ua;
      const int r = (c & 1) ? ua : ub;
      const float4 wv = *(const float4*)(
          cores + ((((c * 2 + q) * 8 + l) * 8 + r) << 4) + quad * 4);
      h2 p0 = PKRTZ(wv.x, wv.y), p1 = PKRTZ(wv.z, wv.w);
      wf[c][bi] = (h4){p0[0], p0[1], p1[0], p1[1]};
    }

  // ---- hoisted, lane-constant stage-B/E LDS offsets (halfs) [R7b-verified]
  const int hq = nn >> 3, hb = nn & 7;
  const int ctA = (quad < 2) ? ((2 + hq) * 80 + hb * 8 + quad * 4) : ZOFF;
  const int ctB = (quad < 2) ? ( hq      * 80 + hb * 8 + quad * 4) : ZOFF;
  const int dA  = (quad < 2) ? ((4 + hq) * 80 + hb * 8 + quad * 4) : ZOFF;
  const int dB  = (quad < 2) ? ((6 + hq) * 80 + hb * 8 + quad * 4) : ZOFF;
  const int ctW = (hq * 2 + (quad >> 1)) * CDROW + hb * 8 + (quad & 1) * 4;
  const int dW  = (4 + (quad >> 1) * 2 + hq) * CDROW + hb * 8 + (quad & 1) * 4;
  const int eA  = (nn >> 2) * CDSTR + (nn & 3) * CDROW + quad * 4;
  const int eB  = (nn >> 2) * CDSTR + (4 + (nn & 3)) * CDROW + quad * 4;
  const bool sW = ((nn >> 2) == quad);
  const int sWo = quad * SS + (nn & 3) * 4;
  const int sRo = quad * SS + (nn & 3) * 4 + (nn >> 2);

  // block = (b, y, x-quarter)
  const int blk = blockIdx.x;
  const int by  = blk >> 2;
  const int b   = by / 127;
  const int y   = by - b * 127;
  const int xq  = (blk & 3) * 32;
  const float* rowbase = ch + (size_t)((b * NH + y) * NW) * 4;
  float* obase = out + (size_t)((b * HO + y) * WO) * 16;

  float  a0[2][4];
  float4 a1[2][4];
  auto loadch = [&](int xtile, int bufi) {
#pragma unroll
    for (int c = 0; c < 4; ++c) {
      int col = xtile + x8 + (c & 1);
      col = col > 127 ? 127 : col;
      const float* cp = rowbase + (((c >> 1) * NW) + col) * 4;
      a0[bufi][c] = cp[quad];
      a1[bufi][c] = *(const float4*)(cp + CH1_OFF);
    }
  };

  // stage A: compute t-tile xtile into tbuf from channel buffer bufi
  auto stageA = [&](int bufi) {
    h4 bf[4];
#pragma unroll
    for (int c = 0; c < 4; ++c) {
      const float s = a0[bufi][c];
      const float4 v = a1[bufi][c];
      h2 p0 = PKRTZ(s * v.x, s * v.y), p1 = PKRTZ(s * v.z, s * v.w);
      bf[c] = (h4){p0[0], p0[1], p1[0], p1[1]};
    }
#pragma unroll
    for (int c = 0; c < 4; ++c)
#pragma unroll
      for (int bi = 0; bi < 8; ++bi) {
        f4 acc = mfma16(wf[c][bi], bf[c], F4Z);
        h2 p0 = PKRTZ(acc[0], acc[1]), p1 = PKRTZ(acc[2], acc[3]);
        if (wr)
          *(h4*)(wrbase + c * 160 + bi * 16 + (bi >= 4 ? 16 : 0)) =
              (h4){p0[0], p0[1], p1[0], p1[1]};
      }
  };

  // prologue: channels for tiles 0,1; stage A(0)
  loadch(xq, 0);
  loadch(xq + 8, 1);
  stageA(0);
  PIN();

#pragma unroll
  for (int t = 0; t < 4; ++t) {
    // ---- stage B for ALL 8 px: 16 independent read->MFMA->write chains
#pragma unroll
    for (int p8 = 0; p8 < 8; ++p8) {
      const __fp16* slot = tbuf + p8 * PXSTR;
      __fp16* cd = cdb + p8 * CDSTR;
      h4 a1f = *(const h4*)(slot + ctA);
      h4 b1f = *(const h4*)(slot + ctB);
      f4 c0 = mfma16(a1f, b1f, F4Z);
      h2 u0 = PKRTZ(c0[0], c0[1]), u1 = PKRTZ(c0[2], c0[3]);
      *(h4*)(cd + ctW) = (h4){u0[0], u0[1], u1[0], u1[1]};
      h4 a2f = *(const h4*)(slot + dA);
      h4 b2f = *(const h4*)(slot + dB);
      f4 d0 = mfma16(a2f, b2f, F4Z);
      h2 v0 = PKRTZ(d0[0], d0[1]), v1 = PKRTZ(d0[2], d0[3]);
      *(h4*)(cd + dW) = (h4){v0[0], v0[1], v1[0], v1[1]};
    }
    PIN();

    // ---- issue all 16 E-reads (both 4-px groups) up front
    h4 ea[2][4], eb[2][4];
#pragma unroll
    for (int g = 0; g < 2; ++g) {
      const __fp16* cdg = cdb + g * 4 * CDSTR;
#pragma unroll
      for (int kb = 0; kb < 4; ++kb) {
        ea[g][kb] = *(const h4*)(cdg + eA + kb * 16);
        eb[g][kb] = *(const h4*)(cdg + eB + kb * 16);
      }
    }

    // ---- stage A(t+1): independent MFMA work hiding the E-read latency
    if (t < 3) {
      stageA((t + 1) & 1);
      if (t < 2) loadch(xq + (t + 2) * 8, t & 1);  // prefetch tile t+2
    }

    // ---- E MFMAs (2 independent 2-chains per group) + sbuf transpose
    f4 ev[2];
#pragma unroll
    for (int g = 0; g < 2; ++g) {
      f4 e0 = mfma16(ea[g][0], eb[g][0], F4Z);
      f4 e1 = mfma16(ea[g][1], eb[g][1], F4Z);
      e0 = mfma16(ea[g][2], eb[g][2], e0);
      e1 = mfma16(ea[g][3], eb[g][3], e1);
      ev[g] = e0 + e1;
      if (sW) *(float4*)(sbuf[g] + sWo) =
          make_float4(ev[g][0], ev[g][1], ev[g][2], ev[g][3]);
    }
    PIN();

    // ---- coalesced stores: lane (quad=px, nn=o16), 256B per group
#pragma unroll
    for (int g = 0; g < 2; ++g) {
      const float v = sbuf[g][sRo];
      const int x4 = xq + t * 8 + g * 4 + quad;
      if (x4 < WO) obase[x4 * 16 + nn] = v;
    }
    PIN();
  }
}

extern "C" void kernel_launch(void* const* d_in, const int* in_sizes, int n_in,
                              void* d_out, int out_size, void* d_ws, size_t ws_size,
                              hipStream_t stream) {
  (void)in_sizes; (void)n_in; (void)d_ws; (void)ws_size; (void)out_size;
  const float* ch    = (const float*)d_in[0];  // [2,8,128,128,4] f32
  const float* cores = (const float*)d_in[1];  // [4,2,8,8,4,4]   f32
  float* out = (float*)d_out;                  // [8,127,127,16]  f32
  convsbs_fused<<<8 * 127 * 4, 64, 0, stream>>>(ch, cores, out);
}